// Round 3
// baseline (343.702 us; speedup 1.0000x reference)
//
#include <hip/hip_runtime.h>

typedef __bf16 bf16;
typedef __bf16 bf16x4 __attribute__((ext_vector_type(4)));
typedef __bf16 bf16x8 __attribute__((ext_vector_type(8)));
typedef float  f32x4  __attribute__((ext_vector_type(4)));

constexpr int Bb = 8, Ss = 1024, Dd = 1024, Hh = 16, HDd = 64;
constexpr int Mm = Bb * Ss;   // 8192
constexpr int Kk = 1024;

// ---------------- fused cast f32 -> bf16 (5 segments, float4 chunks) ----------------
struct CastArgs {
  const float* src[5];
  bf16* dst[5];
  int cum[5];
};
__global__ void cast_all(CastArgs a, int tot) {
  int i = blockIdx.x * blockDim.x + threadIdx.x;
  if (i >= tot) return;
  int s, base;
  if (i < a.cum[0])      { s = 0; base = 0; }
  else if (i < a.cum[1]) { s = 1; base = a.cum[0]; }
  else if (i < a.cum[2]) { s = 2; base = a.cum[1]; }
  else if (i < a.cum[3]) { s = 3; base = a.cum[2]; }
  else                   { s = 4; base = a.cum[3]; }
  int j = i - base;
  float4 v = reinterpret_cast<const float4*>(a.src[s])[j];
  bf16x4 o = { (bf16)v.x, (bf16)v.y, (bf16)v.z, (bf16)v.w };
  reinterpret_cast<bf16x4*>(a.dst[s])[j] = o;
}

// ---------------- shared NT GEMM core: 128x128 tile, BK=64, XOR-swizzled LDS ----------------
__device__ __forceinline__ void gemm_loop(const bf16* __restrict__ A, const bf16* __restrict__ Bm,
                                          int bm, int bn, unsigned char* As, unsigned char* Bs,
                                          int w, int lane, int l15, int g, f32x4 (&acc)[4][4]) {
  const bf16* srcA[4];
  const bf16* srcB[4];
#pragma unroll
  for (int i = 0; i < 4; ++i) {
    int gch = (w * 4 + i) * 64 + lane;  // chunk id 0..1023
    int r = gch >> 3, c = gch & 7, cs = c ^ (r & 7);
    srcA[i] = A  + (size_t)(bm * 128 + r) * Kk + cs * 8;
    srcB[i] = Bm + (size_t)(bn * 128 + r) * Kk + cs * 8;
  }
  for (int kt = 0; kt < Kk / 64; ++kt) {
    __syncthreads();
#pragma unroll
    for (int i = 0; i < 4; ++i) {
      __builtin_amdgcn_global_load_lds(
          (const __attribute__((address_space(1))) void*)(srcA[i] + kt * 64),
          (__attribute__((address_space(3))) void*)(As + (w * 4 + i) * 1024), 16, 0, 0);
      __builtin_amdgcn_global_load_lds(
          (const __attribute__((address_space(1))) void*)(srcB[i] + kt * 64),
          (__attribute__((address_space(3))) void*)(Bs + (w * 4 + i) * 1024), 16, 0, 0);
    }
    __syncthreads();
#pragma unroll
    for (int kk = 0; kk < 2; ++kk) {
      const int kb = kk * 64 + g * 16;
      bf16x8 af[4], bfr[4];
#pragma unroll
      for (int mi = 0; mi < 4; ++mi) {
        int row = ((w >> 1) * 64) + mi * 16 + l15;
        af[mi] = *reinterpret_cast<const bf16x8*>(As + row * 128 + (kb ^ ((row & 7) << 4)));
      }
#pragma unroll
      for (int ni = 0; ni < 4; ++ni) {
        int row = ((w & 1) * 64) + ni * 16 + l15;
        bfr[ni] = *reinterpret_cast<const bf16x8*>(Bs + row * 128 + (kb ^ ((row & 7) << 4)));
      }
#pragma unroll
      for (int mi = 0; mi < 4; ++mi)
#pragma unroll
        for (int ni = 0; ni < 4; ++ni)
          acc[mi][ni] = __builtin_amdgcn_mfma_f32_16x16x32_bf16(af[mi], bfr[ni], acc[mi][ni], 0, 0, 0);
    }
  }
}

// ---------------- fused QKV projection ----------------
// z=0: Q = (x@Wq^T + bq)*0.125 -> [b,h,s,hd]; z=1: K -> [b,h,s,hd]; z=2: V^T -> [b,h,hd,s]
__global__ __launch_bounds__(256) void gemm_qkv(const bf16* __restrict__ x,
                                                const bf16* __restrict__ wq, const bf16* __restrict__ wk,
                                                const bf16* __restrict__ wv,
                                                const float* __restrict__ bq, const float* __restrict__ bk,
                                                const float* __restrict__ bv,
                                                bf16* __restrict__ Qo, bf16* __restrict__ Ko,
                                                bf16* __restrict__ Vto) {
  const int tid = threadIdx.x;
  const int lane = tid & 63;
  const int w = tid >> 6;
  const int l15 = lane & 15, g = lane >> 4;
  const int z = blockIdx.z;

  const bf16* A; const bf16* Bm; int bm, bn;
  if (z < 2) { A = x; Bm = z ? wk : wq; bm = blockIdx.x; bn = blockIdx.y; }
  else       { A = wv; Bm = x;          bm = blockIdx.y; bn = blockIdx.x; }

  __shared__ __align__(16) unsigned char As[128 * 128];
  __shared__ __align__(16) unsigned char Bs[128 * 128];
  f32x4 acc[4][4] = {};
  gemm_loop(A, Bm, bm, bn, As, Bs, w, lane, l15, g, acc);

  const int wr = (w >> 1) * 64, wc = (w & 1) * 64;
  if (z < 2) {
    const float* bias = z ? bk : bq;
    bf16* out = z ? Ko : Qo;
    const float scale = z ? 1.f : 0.125f;
#pragma unroll
    for (int ni = 0; ni < 4; ++ni) {
      int col = bn * 128 + wc + ni * 16 + l15;
      float bv_ = bias[col];
#pragma unroll
      for (int mi = 0; mi < 4; ++mi)
#pragma unroll
        for (int r = 0; r < 4; ++r) {
          int row = bm * 128 + wr + mi * 16 + g * 4 + r;
          float val = (acc[mi][ni][r] + bv_) * scale;
          size_t adr = ((size_t)((row >> 10) * Hh + (col >> 6)) * Ss + (row & 1023)) * HDd + (col & 63);
          out[adr] = (bf16)val;
        }
    }
  } else {  // V^T: row = d-index, col = bs-index, bias per row
#pragma unroll
    for (int mi = 0; mi < 4; ++mi)
#pragma unroll
      for (int r = 0; r < 4; ++r) {
        int row = bm * 128 + wr + mi * 16 + g * 4 + r;
        float bv_ = bv[row];
#pragma unroll
        for (int ni = 0; ni < 4; ++ni) {
          int col = bn * 128 + wc + ni * 16 + l15;
          size_t adr = ((size_t)((col >> 10) * Hh + (row >> 6)) * HDd + (row & 63)) * Ss + (col & 1023);
          Vto[adr] = (bf16)(acc[mi][ni][r] + bv_);
        }
      }
  }
}

// ---------------- final projection: out = ctx @ Wf^T + bf (f32) ----------------
__global__ __launch_bounds__(256) void gemm_out(const bf16* __restrict__ A, const bf16* __restrict__ Bm,
                                                const float* __restrict__ bias, float* __restrict__ out) {
  const int tid = threadIdx.x;
  const int lane = tid & 63;
  const int w = tid >> 6;
  const int l15 = lane & 15, g = lane >> 4;
  const int bn = blockIdx.x, bm = blockIdx.y;
  __shared__ __align__(16) unsigned char As[128 * 128];
  __shared__ __align__(16) unsigned char Bs[128 * 128];
  f32x4 acc[4][4] = {};
  gemm_loop(A, Bm, bm, bn, As, Bs, w, lane, l15, g, acc);
  const int wr = (w >> 1) * 64, wc = (w & 1) * 64;
#pragma unroll
  for (int ni = 0; ni < 4; ++ni) {
    int col = bn * 128 + wc + ni * 16 + l15;
    float bv_ = bias[col];
#pragma unroll
    for (int mi = 0; mi < 4; ++mi)
#pragma unroll
      for (int r = 0; r < 4; ++r) {
        int row = bm * 128 + wr + mi * 16 + g * 4 + r;
        out[(size_t)row * Dd + col] = acc[mi][ni][r] + bv_;
      }
  }
}

// ---------------- fused attention ----------------
// grid: BH*8 blocks, 512 threads = 8 waves, wave owns 16 q rows.
// Swapped QK^T: sc = mfma(K_frag, Q_frag) -> D col (lane&15) = q row, D rows (g*4+r) = 4
// consecutive k positions per lane => float4 probs stores, b64 Ps writes, 2-shuffle l-reduce.
// K double-buffered in LDS (1 barrier per kt, T3 2-phase recipe); V read straight from L2
// (128 KB/head, shared by 8 blocks -> LDS staging would be pure overhead).
__global__ __launch_bounds__(512) void attn_fused(const bf16* __restrict__ Q,
                                                  const bf16* __restrict__ Kt,
                                                  const bf16* __restrict__ Vt,
                                                  float* __restrict__ probs,
                                                  bf16* __restrict__ ctx) {
  const int tid = threadIdx.x;
  const int lane = tid & 63;
  const int w = tid >> 6;
  const int l15 = lane & 15, g = lane >> 4;
  const int bh = blockIdx.x >> 3;
  const int qt = blockIdx.x & 7;
  const int q0 = qt * 128 + w * 16;

  __shared__ __align__(16) unsigned char Ks[2][128 * 128];  // 32 KB double-buffered K tile
  __shared__ __align__(16) bf16 Ps[8][16][40];              // 10 KB per-wave P chunk (32 k)

  // Q fragment (B-operand): lane holds Q[q0+l15][g*8..+7] and +32 (pre-scaled by 1/8)
  bf16x8 qf0, qf1;
  {
    const bf16* qp = Q + ((size_t)bh * Ss + q0 + l15) * HDd + g * 8;
    qf0 = *reinterpret_cast<const bf16x8*>(qp);
    qf1 = *reinterpret_cast<const bf16x8*>(qp + 32);
  }
  const bf16* kbase = Kt + (size_t)bh * Ss * HDd;
  const bf16* vbase = Vt + (size_t)bh * HDd * Ss;

  // K staging source (pre-swizzled per 16B chunk: chunk c of row r holds source chunk c^(r&7))
  const bf16* ksrc[2];
#pragma unroll
  for (int i = 0; i < 2; ++i) {
    int chunk = i * 512 + tid;
    int kr = chunk >> 3, kc = (chunk & 7) ^ (kr & 7);
    ksrc[i] = kbase + (size_t)kr * HDd + kc * 8;
  }

#define STAGE_K(buf, kt)                                                                   \
  {                                                                                        \
    _Pragma("unroll") for (int i = 0; i < 2; ++i)                                          \
        __builtin_amdgcn_global_load_lds(                                                  \
            (const __attribute__((address_space(1))) void*)(ksrc[i] + (kt) * 128 * HDd),   \
            (__attribute__((address_space(3))) void*)(Ks[buf] + (i * 512 + w * 64) * 16),  \
            16, 0, 0);                                                                     \
  }

  auto kread = [&](int buf, int nk, int half) -> bf16x8 {
    int row = nk * 16 + l15;
    int chunk = (half * 4 + g) ^ (row & 7);
    return *reinterpret_cast<const bf16x8*>(Ks[buf] + row * 128 + chunk * 16);
  };

  // ---- pass 1: row sum of exp(score); sc[r] belongs to q = l15 ----
  float lr0 = 0.f, lr1 = 0.f, lr2 = 0.f, lr3 = 0.f;
  STAGE_K(0, 0);
  __syncthreads();
  int cur = 0;
  for (int kt = 0; kt < 8; ++kt) {
    if (kt < 7) STAGE_K(cur ^ 1, kt + 1);
#pragma unroll
    for (int nk = 0; nk < 8; ++nk) {
      f32x4 sc = {0.f, 0.f, 0.f, 0.f};
      sc = __builtin_amdgcn_mfma_f32_16x16x32_bf16(kread(cur, nk, 0), qf0, sc, 0, 0, 0);
      sc = __builtin_amdgcn_mfma_f32_16x16x32_bf16(kread(cur, nk, 1), qf1, sc, 0, 0, 0);
      lr0 += __expf(sc[0]); lr1 += __expf(sc[1]);
      lr2 += __expf(sc[2]); lr3 += __expf(sc[3]);
    }
    __syncthreads();
    cur ^= 1;
  }
  // q = l15; sum partials across the 4 g-groups (lane bits 4,5)
  float lsum = (lr0 + lr1) + (lr2 + lr3);
  lsum += __shfl_xor(lsum, 16, 64);
  lsum += __shfl_xor(lsum, 32, 64);
  const float rl = 1.f / lsum;

  float* const prow = probs + ((size_t)bh * Ss + q0 + l15) * Ss;
  f32x4 cacc[4] = {};

  // ---- pass 2 (kt reversed: K7 still resident in buf1) ----
  cur = 1;
  for (int kt = 7; kt >= 0; --kt) {
    if (kt > 0) STAGE_K(cur ^ 1, kt - 1);
#pragma unroll
    for (int nkp = 0; nkp < 4; ++nkp) {
#pragma unroll
      for (int h = 0; h < 2; ++h) {
        int nk = nkp * 2 + h;
        f32x4 sc = {0.f, 0.f, 0.f, 0.f};
        sc = __builtin_amdgcn_mfma_f32_16x16x32_bf16(kread(cur, nk, 0), qf0, sc, 0, 0, 0);
        sc = __builtin_amdgcn_mfma_f32_16x16x32_bf16(kread(cur, nk, 1), qf1, sc, 0, 0, 0);
        f32x4 pv;
#pragma unroll
        for (int r = 0; r < 4; ++r) pv[r] = __expf(sc[r]) * rl;
        *reinterpret_cast<f32x4*>(prow + kt * 128 + nk * 16 + g * 4) = pv;  // 16 rows x 64B/instr
        bf16x4 pb = { (bf16)pv[0], (bf16)pv[1], (bf16)pv[2], (bf16)pv[3] };
        *reinterpret_cast<bf16x4*>(&Ps[w][l15][h * 16 + g * 4]) = pb;       // one ds_write_b64
      }
      // PV over this 32-wide k chunk; P from wave-private LDS, V straight from L2
      bf16x8 pf = *reinterpret_cast<const bf16x8*>(&Ps[w][l15][g * 8]);
#pragma unroll
      for (int ni = 0; ni < 4; ++ni) {
        bf16x8 vf = *reinterpret_cast<const bf16x8*>(
            vbase + (size_t)(ni * 16 + l15) * Ss + kt * 128 + nkp * 32 + g * 8);
        cacc[ni] = __builtin_amdgcn_mfma_f32_16x16x32_bf16(pf, vf, cacc[ni], 0, 0, 0);
      }
    }
    __syncthreads();
    cur ^= 1;
  }
#undef STAGE_K

  // ctx: [b][s][h*64+hd] bf16 (PV D layout: col=hd, row=g*4+r=q offset)
  const int bb = bh >> 4, hh = bh & 15;
#pragma unroll
  for (int ni = 0; ni < 4; ++ni)
#pragma unroll
    for (int r = 0; r < 4; ++r) {
      int q = q0 + g * 4 + r;
      ctx[((size_t)bb * Ss + q) * Dd + hh * 64 + ni * 16 + l15] = (bf16)cacc[ni][r];
    }
}

// ---------------- launch ----------------
extern "C" void kernel_launch(void* const* d_in, const int* in_sizes, int n_in,
                              void* d_out, int out_size, void* d_ws, size_t ws_size,
                              hipStream_t stream) {
  (void)in_sizes; (void)n_in; (void)out_size; (void)ws_size;
  const float* x   = (const float*)d_in[0];
  const float* Wq  = (const float*)d_in[1];
  const float* bq  = (const float*)d_in[2];
  const float* Wk  = (const float*)d_in[3];
  const float* bk  = (const float*)d_in[4];
  const float* Wv  = (const float*)d_in[5];
  const float* bv  = (const float*)d_in[6];
  const float* Wf  = (const float*)d_in[7];
  const float* bfp = (const float*)d_in[8];

  char* ws = (char*)d_ws;
  size_t off = 0;
  auto alloc = [&](size_t n) { void* p = ws + off; off += (n + 255) & ~(size_t)255; return p; };
  bf16* xb   = (bf16*)alloc((size_t)Mm * Dd * 2);
  bf16* wqb  = (bf16*)alloc((size_t)Dd * Dd * 2);
  bf16* wkb  = (bf16*)alloc((size_t)Dd * Dd * 2);
  bf16* wvb  = (bf16*)alloc((size_t)Dd * Dd * 2);
  bf16* wfb  = (bf16*)alloc((size_t)Dd * Dd * 2);
  bf16* Qb   = (bf16*)alloc((size_t)Mm * Dd * 2);
  bf16* Kb   = (bf16*)alloc((size_t)Mm * Dd * 2);
  bf16* Vtb  = (bf16*)alloc((size_t)Mm * Dd * 2);
  bf16* ctxb = (bf16*)alloc((size_t)Mm * Dd * 2);

  CastArgs ca;
  ca.src[0] = x;  ca.dst[0] = xb;  int n0 = Mm * Dd / 4;
  ca.src[1] = Wq; ca.dst[1] = wqb; int nw = Dd * Dd / 4;
  ca.src[2] = Wk; ca.dst[2] = wkb;
  ca.src[3] = Wv; ca.dst[3] = wvb;
  ca.src[4] = Wf; ca.dst[4] = wfb;
  ca.cum[0] = n0; ca.cum[1] = n0 + nw; ca.cum[2] = n0 + 2 * nw;
  ca.cum[3] = n0 + 3 * nw; ca.cum[4] = n0 + 4 * nw;
  int tot = ca.cum[4];
  cast_all<<<(tot + 255) / 256, 256, 0, stream>>>(ca, tot);

  gemm_qkv<<<dim3(Mm / 128, Dd / 128, 3), 256, 0, stream>>>(xb, wqb, wkb, wvb, bq, bk, bv, Qb, Kb, Vtb);

  float* probs = (float*)d_out + (size_t)Mm * Dd;
  attn_fused<<<dim3(Bb * Hh * 8), 512, 0, stream>>>(Qb, Kb, Vtb, probs, ctxb);

  gemm_out<<<dim3(Dd / 128, Mm / 128), 256, 0, stream>>>(ctxb, wfb, bfp, (float*)d_out);
}

// Round 4
// 310.873 us; speedup vs baseline: 1.1056x; 1.1056x over previous
//
#include <hip/hip_runtime.h>

typedef __bf16 bf16;
typedef __bf16 bf16x4 __attribute__((ext_vector_type(4)));
typedef __bf16 bf16x8 __attribute__((ext_vector_type(8)));
typedef float  f32x4  __attribute__((ext_vector_type(4)));

constexpr int Bb = 8, Ss = 1024, Dd = 1024, Hh = 16, HDd = 64;
constexpr int Mm = Bb * Ss;   // 8192
constexpr int Kk = 1024;

// ---------------- fused cast f32 -> bf16 (5 segments, float4 chunks) ----------------
struct CastArgs {
  const float* src[5];
  bf16* dst[5];
  int cum[5];
};
__global__ void cast_all(CastArgs a, int tot) {
  int i = blockIdx.x * blockDim.x + threadIdx.x;
  if (i >= tot) return;
  int s, base;
  if (i < a.cum[0])      { s = 0; base = 0; }
  else if (i < a.cum[1]) { s = 1; base = a.cum[0]; }
  else if (i < a.cum[2]) { s = 2; base = a.cum[1]; }
  else if (i < a.cum[3]) { s = 3; base = a.cum[2]; }
  else                   { s = 4; base = a.cum[3]; }
  int j = i - base;
  float4 v = reinterpret_cast<const float4*>(a.src[s])[j];
  bf16x4 o = { (bf16)v.x, (bf16)v.y, (bf16)v.z, (bf16)v.w };
  reinterpret_cast<bf16x4*>(a.dst[s])[j] = o;
}

// ---------------- shared NT GEMM core: 128x128 tile, BK=64, XOR-swizzled LDS ----------------
__device__ __forceinline__ void gemm_loop(const bf16* __restrict__ A, const bf16* __restrict__ Bm,
                                          int bm, int bn, unsigned char* As, unsigned char* Bs,
                                          int w, int lane, int l15, int g, f32x4 (&acc)[4][4]) {
  const bf16* srcA[4];
  const bf16* srcB[4];
#pragma unroll
  for (int i = 0; i < 4; ++i) {
    int gch = (w * 4 + i) * 64 + lane;  // chunk id 0..1023
    int r = gch >> 3, c = gch & 7, cs = c ^ (r & 7);
    srcA[i] = A  + (size_t)(bm * 128 + r) * Kk + cs * 8;
    srcB[i] = Bm + (size_t)(bn * 128 + r) * Kk + cs * 8;
  }
  for (int kt = 0; kt < Kk / 64; ++kt) {
    __syncthreads();
#pragma unroll
    for (int i = 0; i < 4; ++i) {
      __builtin_amdgcn_global_load_lds(
          (const __attribute__((address_space(1))) void*)(srcA[i] + kt * 64),
          (__attribute__((address_space(3))) void*)(As + (w * 4 + i) * 1024), 16, 0, 0);
      __builtin_amdgcn_global_load_lds(
          (const __attribute__((address_space(1))) void*)(srcB[i] + kt * 64),
          (__attribute__((address_space(3))) void*)(Bs + (w * 4 + i) * 1024), 16, 0, 0);
    }
    __syncthreads();
#pragma unroll
    for (int kk = 0; kk < 2; ++kk) {
      const int kb = kk * 64 + g * 16;
      bf16x8 af[4], bfr[4];
#pragma unroll
      for (int mi = 0; mi < 4; ++mi) {
        int row = ((w >> 1) * 64) + mi * 16 + l15;
        af[mi] = *reinterpret_cast<const bf16x8*>(As + row * 128 + (kb ^ ((row & 7) << 4)));
      }
#pragma unroll
      for (int ni = 0; ni < 4; ++ni) {
        int row = ((w & 1) * 64) + ni * 16 + l15;
        bfr[ni] = *reinterpret_cast<const bf16x8*>(Bs + row * 128 + (kb ^ ((row & 7) << 4)));
      }
#pragma unroll
      for (int mi = 0; mi < 4; ++mi)
#pragma unroll
        for (int ni = 0; ni < 4; ++ni)
          acc[mi][ni] = __builtin_amdgcn_mfma_f32_16x16x32_bf16(af[mi], bfr[ni], acc[mi][ni], 0, 0, 0);
    }
  }
}

// ---------------- fused QKV projection ----------------
// z=0: Q = (x@Wq^T + bq)*0.125 -> [b,h,s,hd]; z=1: K -> [b,h,s,hd]; z=2: V^T -> [b,h,hd,s]
__global__ __launch_bounds__(256) void gemm_qkv(const bf16* __restrict__ x,
                                                const bf16* __restrict__ wq, const bf16* __restrict__ wk,
                                                const bf16* __restrict__ wv,
                                                const float* __restrict__ bq, const float* __restrict__ bk,
                                                const float* __restrict__ bv,
                                                bf16* __restrict__ Qo, bf16* __restrict__ Ko,
                                                bf16* __restrict__ Vto) {
  const int tid = threadIdx.x;
  const int lane = tid & 63;
  const int w = tid >> 6;
  const int l15 = lane & 15, g = lane >> 4;
  const int z = blockIdx.z;

  const bf16* A; const bf16* Bm; int bm, bn;
  if (z < 2) { A = x; Bm = z ? wk : wq; bm = blockIdx.x; bn = blockIdx.y; }
  else       { A = wv; Bm = x;          bm = blockIdx.y; bn = blockIdx.x; }

  __shared__ __align__(16) unsigned char As[128 * 128];
  __shared__ __align__(16) unsigned char Bs[128 * 128];
  f32x4 acc[4][4] = {};
  gemm_loop(A, Bm, bm, bn, As, Bs, w, lane, l15, g, acc);

  const int wr = (w >> 1) * 64, wc = (w & 1) * 64;
  if (z < 2) {
    const float* bias = z ? bk : bq;
    bf16* out = z ? Ko : Qo;
    const float scale = z ? 1.f : 0.125f;
#pragma unroll
    for (int ni = 0; ni < 4; ++ni) {
      int col = bn * 128 + wc + ni * 16 + l15;
      float bv_ = bias[col];
#pragma unroll
      for (int mi = 0; mi < 4; ++mi)
#pragma unroll
        for (int r = 0; r < 4; ++r) {
          int row = bm * 128 + wr + mi * 16 + g * 4 + r;
          float val = (acc[mi][ni][r] + bv_) * scale;
          size_t adr = ((size_t)((row >> 10) * Hh + (col >> 6)) * Ss + (row & 1023)) * HDd + (col & 63);
          out[adr] = (bf16)val;
        }
    }
  } else {  // V^T: row = d-index, col = bs-index, bias per row
#pragma unroll
    for (int mi = 0; mi < 4; ++mi)
#pragma unroll
      for (int r = 0; r < 4; ++r) {
        int row = bm * 128 + wr + mi * 16 + g * 4 + r;
        float bv_ = bv[row];
#pragma unroll
        for (int ni = 0; ni < 4; ++ni) {
          int col = bn * 128 + wc + ni * 16 + l15;
          size_t adr = ((size_t)((col >> 10) * Hh + (row >> 6)) * HDd + (row & 63)) * Ss + (col & 1023);
          Vto[adr] = (bf16)(acc[mi][ni][r] + bv_);
        }
      }
  }
}

// ---------------- final projection: out = ctx @ Wf^T + bf (f32) ----------------
__global__ __launch_bounds__(256) void gemm_out(const bf16* __restrict__ A, const bf16* __restrict__ Bm,
                                                const float* __restrict__ bias, float* __restrict__ out) {
  const int tid = threadIdx.x;
  const int lane = tid & 63;
  const int w = tid >> 6;
  const int l15 = lane & 15, g = lane >> 4;
  const int bn = blockIdx.x, bm = blockIdx.y;
  __shared__ __align__(16) unsigned char As[128 * 128];
  __shared__ __align__(16) unsigned char Bs[128 * 128];
  f32x4 acc[4][4] = {};
  gemm_loop(A, Bm, bm, bn, As, Bs, w, lane, l15, g, acc);
  const int wr = (w >> 1) * 64, wc = (w & 1) * 64;
#pragma unroll
  for (int ni = 0; ni < 4; ++ni) {
    int col = bn * 128 + wc + ni * 16 + l15;
    float bv_ = bias[col];
#pragma unroll
    for (int mi = 0; mi < 4; ++mi)
#pragma unroll
      for (int r = 0; r < 4; ++r) {
        int row = bm * 128 + wr + mi * 16 + g * 4 + r;
        out[(size_t)row * Dd + col] = acc[mi][ni][r] + bv_;
      }
  }
}

// ---------------- fused attention ----------------
// 1024 blocks, 512 threads = 8 waves, wave owns 16 q rows. KVBLK=64, 16 kt steps.
// XCD-aware decode: all 8 q-tile blocks of a head share bid%8 (same XCD) -> K/V L2-resident
// (16 heads x 256 KB = 4 MB per XCD). Swapped QK^T (mfma(K,Q)): lane l15 = q row, g*4+r = k
// positions -> f32x4 nontemporal probs stores (bypass L2), 2-shuffle l-reduce.
// K and V double-buffered in LDS via global_load_lds (compute reads ONLY LDS: no register
// VMEM in the MFMA phase, so staging floats to the single per-kt barrier).
__global__ __launch_bounds__(512) void attn_fused(const bf16* __restrict__ Q,
                                                  const bf16* __restrict__ Kt,
                                                  const bf16* __restrict__ Vt,
                                                  float* __restrict__ probs,
                                                  bf16* __restrict__ ctx) {
  const int tid = threadIdx.x;
  const int lane = tid & 63;
  const int w = tid >> 6;
  const int l15 = lane & 15, g = lane >> 4;
  const int bid = blockIdx.x;
  const int bh = (bid & 7) * 16 + ((bid >> 3) & 15);  // same head -> same bid%8 -> same XCD
  const int qt = bid >> 7;
  const int q0 = qt * 128 + w * 16;

  __shared__ __align__(16) unsigned char Ks[2][8192];  // 64 kpos x 128B, chunk-XOR swizzled
  __shared__ __align__(16) unsigned char Vs[2][8192];  // 64 hd   x 128B, chunk-XOR swizzled
  __shared__ __align__(16) bf16 Ps[8][16][40];         // per-wave P chunk (32 k + pad)

  // Q fragment (B-operand): lane holds Q[q0+l15][g*8..+7] and +32 (pre-scaled by 1/8)
  bf16x8 qf0, qf1;
  {
    const bf16* qp = Q + ((size_t)bh * Ss + q0 + l15) * HDd + g * 8;
    qf0 = *reinterpret_cast<const bf16x8*>(qp);
    qf1 = *reinterpret_cast<const bf16x8*>(qp + 32);
  }
  const bf16* kbase = Kt + (size_t)bh * Ss * HDd;
  const bf16* vbase = Vt + (size_t)bh * HDd * Ss;

  // staging sources: 512 chunks of 16B = 64 rows x 8 chunks, source chunk pre-swizzled
  // (LDS chunk c of row r receives source chunk c^(r&7); global_load_lds dest is linear)
  const int sr = tid >> 3, scn = (tid & 7) ^ (sr & 7);
  const bf16* const ksrc = kbase + (size_t)sr * HDd + scn * 8;
  const bf16* const vsrc = vbase + (size_t)sr * Ss + scn * 8;

#define SK(b, t)                                                                         \
  __builtin_amdgcn_global_load_lds(                                                      \
      (const __attribute__((address_space(1))) void*)(ksrc + (size_t)(t) * 64 * HDd),    \
      (__attribute__((address_space(3))) void*)(Ks[b] + w * 1024), 16, 0, 0)
#define SV(b, t)                                                                         \
  __builtin_amdgcn_global_load_lds(                                                      \
      (const __attribute__((address_space(1))) void*)(vsrc + (t) * 64),                  \
      (__attribute__((address_space(3))) void*)(Vs[b] + w * 1024), 16, 0, 0)

  auto kread = [&](int b, int nk, int half) -> bf16x8 {
    int row = nk * 16 + l15;
    int chunk = (half * 4 + g) ^ (row & 7);
    return *reinterpret_cast<const bf16x8*>(Ks[b] + row * 128 + chunk * 16);
  };
  auto vread = [&](int b, int nkp, int ni) -> bf16x8 {
    int row = ni * 16 + l15;
    int chunk = (nkp * 4 + g) ^ (row & 7);
    return *reinterpret_cast<const bf16x8*>(Vs[b] + row * 128 + chunk * 16);
  };

  // ---- pass 1: row sum of exp(score); lane's q = l15, k = g*4+r within nk*16 ----
  float lr0 = 0.f, lr1 = 0.f, lr2 = 0.f, lr3 = 0.f;
  SK(0, 0);
  __syncthreads();
  int cur = 0;
  for (int kt = 0; kt < 16; ++kt) {
    if (kt < 15) SK(cur ^ 1, kt + 1);
    if (kt == 14) SV(cur ^ 1, 15);  // pre-stage V15 for pass-2 entry
#pragma unroll
    for (int nk = 0; nk < 4; ++nk) {
      f32x4 sc = {0.f, 0.f, 0.f, 0.f};
      sc = __builtin_amdgcn_mfma_f32_16x16x32_bf16(kread(cur, nk, 0), qf0, sc, 0, 0, 0);
      sc = __builtin_amdgcn_mfma_f32_16x16x32_bf16(kread(cur, nk, 1), qf1, sc, 0, 0, 0);
      lr0 += __expf(sc[0]); lr1 += __expf(sc[1]);
      lr2 += __expf(sc[2]); lr3 += __expf(sc[3]);
    }
    __syncthreads();
    cur ^= 1;
  }
  float lsum = (lr0 + lr1) + (lr2 + lr3);
  lsum += __shfl_xor(lsum, 16, 64);
  lsum += __shfl_xor(lsum, 32, 64);
  const float rl = 1.f / lsum;

  float* const prow = probs + ((size_t)bh * Ss + q0 + l15) * Ss;
  f32x4 cacc[4] = {};

  // ---- pass 2 (kt descending: buf1 holds K15+V15; buf0 still holds K14 from pass 1) ----
  cur = 1;
  for (int kt = 15; kt >= 0; --kt) {
    if (kt == 15) { SV(0, 14); }
    else if (kt > 0) { SK(cur ^ 1, kt - 1); SV(cur ^ 1, kt - 1); }
#pragma unroll
    for (int nkp = 0; nkp < 2; ++nkp) {
#pragma unroll
      for (int h = 0; h < 2; ++h) {
        int nk = nkp * 2 + h;
        f32x4 sc = {0.f, 0.f, 0.f, 0.f};
        sc = __builtin_amdgcn_mfma_f32_16x16x32_bf16(kread(cur, nk, 0), qf0, sc, 0, 0, 0);
        sc = __builtin_amdgcn_mfma_f32_16x16x32_bf16(kread(cur, nk, 1), qf1, sc, 0, 0, 0);
        f32x4 pv;
#pragma unroll
        for (int r = 0; r < 4; ++r) pv[r] = __expf(sc[r]) * rl;
        __builtin_nontemporal_store(pv, reinterpret_cast<f32x4*>(prow + kt * 64 + nk * 16 + g * 4));
        bf16x4 pb = { (bf16)pv[0], (bf16)pv[1], (bf16)pv[2], (bf16)pv[3] };
        *reinterpret_cast<bf16x4*>(&Ps[w][l15][h * 16 + g * 4]) = pb;  // one ds_write_b64
      }
      // PV over this 32-wide k chunk; P and V both from LDS (same-wave DS is in-order)
      bf16x8 pf = *reinterpret_cast<const bf16x8*>(&Ps[w][l15][g * 8]);
#pragma unroll
      for (int ni = 0; ni < 4; ++ni)
        cacc[ni] = __builtin_amdgcn_mfma_f32_16x16x32_bf16(pf, vread(cur, nkp, ni), cacc[ni], 0, 0, 0);
    }
    __syncthreads();
    cur ^= 1;
  }
#undef SK
#undef SV

  // ctx: [b][s][h*64+hd] bf16 (PV D layout: row g*4+r = q offset, col l15 = hd)
  const int bb = bh >> 4, hh = bh & 15;
#pragma unroll
  for (int ni = 0; ni < 4; ++ni)
#pragma unroll
    for (int r = 0; r < 4; ++r) {
      int q = q0 + g * 4 + r;
      ctx[((size_t)bb * Ss + q) * Dd + hh * 64 + ni * 16 + l15] = (bf16)cacc[ni][r];
    }
}

// ---------------- launch ----------------
extern "C" void kernel_launch(void* const* d_in, const int* in_sizes, int n_in,
                              void* d_out, int out_size, void* d_ws, size_t ws_size,
                              hipStream_t stream) {
  (void)in_sizes; (void)n_in; (void)out_size; (void)ws_size;
  const float* x   = (const float*)d_in[0];
  const float* Wq  = (const float*)d_in[1];
  const float* bq  = (const float*)d_in[2];
  const float* Wk  = (const float*)d_in[3];
  const float* bk  = (const float*)d_in[4];
  const float* Wv  = (const float*)d_in[5];
  const float* bv  = (const float*)d_in[6];
  const float* Wf  = (const float*)d_in[7];
  const float* bfp = (const float*)d_in[8];

  char* ws = (char*)d_ws;
  size_t off = 0;
  auto alloc = [&](size_t n) { void* p = ws + off; off += (n + 255) & ~(size_t)255; return p; };
  bf16* xb   = (bf16*)alloc((size_t)Mm * Dd * 2);
  bf16* wqb  = (bf16*)alloc((size_t)Dd * Dd * 2);
  bf16* wkb  = (bf16*)alloc((size_t)Dd * Dd * 2);
  bf16* wvb  = (bf16*)alloc((size_t)Dd * Dd * 2);
  bf16* wfb  = (bf16*)alloc((size_t)Dd * Dd * 2);
  bf16* Qb   = (bf16*)alloc((size_t)Mm * Dd * 2);
  bf16* Kb   = (bf16*)alloc((size_t)Mm * Dd * 2);
  bf16* Vtb  = (bf16*)alloc((size_t)Mm * Dd * 2);
  bf16* ctxb = (bf16*)alloc((size_t)Mm * Dd * 2);

  CastArgs ca;
  ca.src[0] = x;  ca.dst[0] = xb;  int n0 = Mm * Dd / 4;
  ca.src[1] = Wq; ca.dst[1] = wqb; int nw = Dd * Dd / 4;
  ca.src[2] = Wk; ca.dst[2] = wkb;
  ca.src[3] = Wv; ca.dst[3] = wvb;
  ca.src[4] = Wf; ca.dst[4] = wfb;
  ca.cum[0] = n0; ca.cum[1] = n0 + nw; ca.cum[2] = n0 + 2 * nw;
  ca.cum[3] = n0 + 3 * nw; ca.cum[4] = n0 + 4 * nw;
  int tot = ca.cum[4];
  cast_all<<<(tot + 255) / 256, 256, 0, stream>>>(ca, tot);

  gemm_qkv<<<dim3(Mm / 128, Dd / 128, 3), 256, 0, stream>>>(xb, wqb, wkb, wvb, bq, bk, bv, Qb, Kb, Vtb);

  float* probs = (float*)d_out + (size_t)Mm * Dd;
  attn_fused<<<dim3(Bb * Hh * 8), 512, 0, stream>>>(Qb, Kb, Vtb, probs, ctxb);

  gemm_out<<<dim3(Dd / 128, Mm / 128), 256, 0, stream>>>(ctxb, wfb, bfp, (float*)d_out);
}

// Round 5
// 264.060 us; speedup vs baseline: 1.3016x; 1.1773x over previous
//
#include <hip/hip_runtime.h>

typedef __bf16 bf16;
typedef __bf16 bf16x4 __attribute__((ext_vector_type(4)));
typedef __bf16 bf16x8 __attribute__((ext_vector_type(8)));
typedef float  f32x4  __attribute__((ext_vector_type(4)));

constexpr int Bb = 8, Ss = 1024, Dd = 1024, Hh = 16, HDd = 64;
constexpr int Mm = Bb * Ss;   // 8192
constexpr int Kk = 1024;

// ---------------- fused cast f32 -> bf16 (5 segments, float4 chunks) ----------------
struct CastArgs {
  const float* src[5];
  bf16* dst[5];
  int cum[5];
};
__global__ void cast_all(CastArgs a, int tot) {
  int i = blockIdx.x * blockDim.x + threadIdx.x;
  if (i >= tot) return;
  int s, base;
  if (i < a.cum[0])      { s = 0; base = 0; }
  else if (i < a.cum[1]) { s = 1; base = a.cum[0]; }
  else if (i < a.cum[2]) { s = 2; base = a.cum[1]; }
  else if (i < a.cum[3]) { s = 3; base = a.cum[2]; }
  else                   { s = 4; base = a.cum[3]; }
  int j = i - base;
  float4 v = reinterpret_cast<const float4*>(a.src[s])[j];
  bf16x4 o = { (bf16)v.x, (bf16)v.y, (bf16)v.z, (bf16)v.w };
  reinterpret_cast<bf16x4*>(a.dst[s])[j] = o;
}

// ---------------- shared NT GEMM core: 128x128 tile, BK=64, XOR-swizzled LDS ----------------
__device__ __forceinline__ void gemm_loop(const bf16* __restrict__ A, const bf16* __restrict__ Bm,
                                          int bm, int bn, unsigned char* As, unsigned char* Bs,
                                          int w, int lane, int l15, int g, f32x4 (&acc)[4][4]) {
  const bf16* srcA[4];
  const bf16* srcB[4];
#pragma unroll
  for (int i = 0; i < 4; ++i) {
    int gch = (w * 4 + i) * 64 + lane;  // chunk id 0..1023
    int r = gch >> 3, c = gch & 7, cs = c ^ (r & 7);
    srcA[i] = A  + (size_t)(bm * 128 + r) * Kk + cs * 8;
    srcB[i] = Bm + (size_t)(bn * 128 + r) * Kk + cs * 8;
  }
  for (int kt = 0; kt < Kk / 64; ++kt) {
    __syncthreads();
#pragma unroll
    for (int i = 0; i < 4; ++i) {
      __builtin_amdgcn_global_load_lds(
          (const __attribute__((address_space(1))) void*)(srcA[i] + kt * 64),
          (__attribute__((address_space(3))) void*)(As + (w * 4 + i) * 1024), 16, 0, 0);
      __builtin_amdgcn_global_load_lds(
          (const __attribute__((address_space(1))) void*)(srcB[i] + kt * 64),
          (__attribute__((address_space(3))) void*)(Bs + (w * 4 + i) * 1024), 16, 0, 0);
    }
    __syncthreads();
#pragma unroll
    for (int kk = 0; kk < 2; ++kk) {
      const int kb = kk * 64 + g * 16;
      bf16x8 af[4], bfr[4];
#pragma unroll
      for (int mi = 0; mi < 4; ++mi) {
        int row = ((w >> 1) * 64) + mi * 16 + l15;
        af[mi] = *reinterpret_cast<const bf16x8*>(As + row * 128 + (kb ^ ((row & 7) << 4)));
      }
#pragma unroll
      for (int ni = 0; ni < 4; ++ni) {
        int row = ((w & 1) * 64) + ni * 16 + l15;
        bfr[ni] = *reinterpret_cast<const bf16x8*>(Bs + row * 128 + (kb ^ ((row & 7) << 4)));
      }
#pragma unroll
      for (int mi = 0; mi < 4; ++mi)
#pragma unroll
        for (int ni = 0; ni < 4; ++ni)
          acc[mi][ni] = __builtin_amdgcn_mfma_f32_16x16x32_bf16(af[mi], bfr[ni], acc[mi][ni], 0, 0, 0);
    }
  }
}

// ---------------- fused QKV projection ----------------
// z=0: Q = (x@Wq^T + bq)*0.125 -> [b,h,s,hd]; z=1: K -> [b,h,s,hd]; z=2: V^T -> [b,h,hd,s]
__global__ __launch_bounds__(256) void gemm_qkv(const bf16* __restrict__ x,
                                                const bf16* __restrict__ wq, const bf16* __restrict__ wk,
                                                const bf16* __restrict__ wv,
                                                const float* __restrict__ bq, const float* __restrict__ bk,
                                                const float* __restrict__ bv,
                                                bf16* __restrict__ Qo, bf16* __restrict__ Ko,
                                                bf16* __restrict__ Vto) {
  const int tid = threadIdx.x;
  const int lane = tid & 63;
  const int w = tid >> 6;
  const int l15 = lane & 15, g = lane >> 4;
  const int z = blockIdx.z;

  const bf16* A; const bf16* Bm; int bm, bn;
  if (z < 2) { A = x; Bm = z ? wk : wq; bm = blockIdx.x; bn = blockIdx.y; }
  else       { A = wv; Bm = x;          bm = blockIdx.y; bn = blockIdx.x; }

  __shared__ __align__(16) unsigned char As[128 * 128];
  __shared__ __align__(16) unsigned char Bs[128 * 128];
  f32x4 acc[4][4] = {};
  gemm_loop(A, Bm, bm, bn, As, Bs, w, lane, l15, g, acc);

  const int wr = (w >> 1) * 64, wc = (w & 1) * 64;
  if (z < 2) {
    const float* bias = z ? bk : bq;
    bf16* out = z ? Ko : Qo;
    const float scale = z ? 1.f : 0.125f;
#pragma unroll
    for (int ni = 0; ni < 4; ++ni) {
      int col = bn * 128 + wc + ni * 16 + l15;
      float bv_ = bias[col];
#pragma unroll
      for (int mi = 0; mi < 4; ++mi)
#pragma unroll
        for (int r = 0; r < 4; ++r) {
          int row = bm * 128 + wr + mi * 16 + g * 4 + r;
          float val = (acc[mi][ni][r] + bv_) * scale;
          size_t adr = ((size_t)((row >> 10) * Hh + (col >> 6)) * Ss + (row & 1023)) * HDd + (col & 63);
          out[adr] = (bf16)val;
        }
    }
  } else {  // V^T: row = d-index, col = bs-index, bias per row
#pragma unroll
    for (int mi = 0; mi < 4; ++mi)
#pragma unroll
      for (int r = 0; r < 4; ++r) {
        int row = bm * 128 + wr + mi * 16 + g * 4 + r;
        float bv_ = bv[row];
#pragma unroll
        for (int ni = 0; ni < 4; ++ni) {
          int col = bn * 128 + wc + ni * 16 + l15;
          size_t adr = ((size_t)((col >> 10) * Hh + (row >> 6)) * HDd + (row & 63)) * Ss + (col & 1023);
          Vto[adr] = (bf16)(acc[mi][ni][r] + bv_);
        }
      }
  }
}

// ---------------- final projection: out = ctx @ Wf^T + bf (f32) ----------------
__global__ __launch_bounds__(256) void gemm_out(const bf16* __restrict__ A, const bf16* __restrict__ Bm,
                                                const float* __restrict__ bias, float* __restrict__ out) {
  const int tid = threadIdx.x;
  const int lane = tid & 63;
  const int w = tid >> 6;
  const int l15 = lane & 15, g = lane >> 4;
  const int bn = blockIdx.x, bm = blockIdx.y;
  __shared__ __align__(16) unsigned char As[128 * 128];
  __shared__ __align__(16) unsigned char Bs[128 * 128];
  f32x4 acc[4][4] = {};
  gemm_loop(A, Bm, bm, bn, As, Bs, w, lane, l15, g, acc);
  const int wr = (w >> 1) * 64, wc = (w & 1) * 64;
#pragma unroll
  for (int ni = 0; ni < 4; ++ni) {
    int col = bn * 128 + wc + ni * 16 + l15;
    float bv_ = bias[col];
#pragma unroll
    for (int mi = 0; mi < 4; ++mi)
#pragma unroll
      for (int r = 0; r < 4; ++r) {
        int row = bm * 128 + wr + mi * 16 + g * 4 + r;
        out[(size_t)row * Dd + col] = acc[mi][ni][r] + bv_;
      }
  }
}

// ---------------- fused attention ----------------
// 1024 blocks, 512 threads = 8 waves, wave owns 16 q rows. KVBLK=128, 8 kt phases per pass.
// 4 LDS slabs of 16KB: K double-buffered in slabs 0/1 (slab = kt&1), V in slabs 2/3.
// Swapped QK^T (mfma(K,Q)): lane l15 = q row, g*4+r = k positions -> f32x4 probs stores,
// 2-shuffle l-reduce. One barrier per phase; staging for kt+1 issued at phase top (compute
// reads ONLY LDS). Pass-1 tail pre-stages K0+V0 so pass 2 runs ascending with slab = kt&1.
// VGPR capped via __launch_bounds__(512,4) -> 4 waves/SIMD = 2 blocks/CU (LDS 74KB x2 fits).
__global__ __launch_bounds__(512, 4) void attn_fused(const bf16* __restrict__ Q,
                                                     const bf16* __restrict__ Kt,
                                                     const bf16* __restrict__ Vt,
                                                     float* __restrict__ probs,
                                                     bf16* __restrict__ ctx) {
  const int tid = threadIdx.x;
  const int lane = tid & 63;
  const int w = tid >> 6;
  const int l15 = lane & 15, g = lane >> 4;
  const int bid = blockIdx.x;
  const int bh = (bid & 7) * 16 + ((bid >> 3) & 15);  // same head -> same bid%8 -> same XCD
  const int qt = bid >> 7;
  const int q0 = qt * 128 + w * 16;

  __shared__ __align__(16) unsigned char KV[4][16384];  // K: slabs 0/1 (128x128B), V: 2/3 (64x256B)
  __shared__ __align__(16) bf16 Ps[8][16][40];          // per-wave P chunk (32 k + pad)

  // Q fragment (B-operand): lane holds Q[q0+l15][g*8..+7] and +32 (pre-scaled by 1/8)
  bf16x8 qf0, qf1;
  {
    const bf16* qp = Q + ((size_t)bh * Ss + q0 + l15) * HDd + g * 8;
    qf0 = *reinterpret_cast<const bf16x8*>(qp);
    qf1 = *reinterpret_cast<const bf16x8*>(qp + 32);
  }
  const bf16* kbase = Kt + (size_t)bh * Ss * HDd;
  const bf16* vbase = Vt + (size_t)bh * HDd * Ss;

  // staging sources (source chunk pre-swizzled; global_load_lds dest = wave base + lane*16)
  // K tile: 1024 chunks = 128 rows x 8;  V tile: 1024 chunks = 64 rows x 16
  const bf16* ksrc[2];
  const bf16* vsrc[2];
#pragma unroll
  for (int i = 0; i < 2; ++i) {
    int ch = i * 512 + tid;
    int kr = ch >> 3, kc = (ch & 7) ^ (kr & 7);
    ksrc[i] = kbase + (size_t)kr * HDd + kc * 8;
    int vr = ch >> 4, vc = (ch & 15) ^ (vr & 15);
    vsrc[i] = vbase + (size_t)vr * Ss + vc * 8;
  }

#define SK(slab, t)                                                                       \
  {                                                                                       \
    _Pragma("unroll") for (int i = 0; i < 2; ++i)                                         \
        __builtin_amdgcn_global_load_lds(                                                 \
            (const __attribute__((address_space(1))) void*)(ksrc[i] + (size_t)(t) * 128 * HDd), \
            (__attribute__((address_space(3))) void*)(KV[slab] + (i * 512 + w * 64) * 16),\
            16, 0, 0);                                                                    \
  }
#define SV(slab, t)                                                                       \
  {                                                                                       \
    _Pragma("unroll") for (int i = 0; i < 2; ++i)                                         \
        __builtin_amdgcn_global_load_lds(                                                 \
            (const __attribute__((address_space(1))) void*)(vsrc[i] + (t) * 128),         \
            (__attribute__((address_space(3))) void*)(KV[slab] + (i * 512 + w * 64) * 16),\
            16, 0, 0);                                                                    \
  }

  auto kread = [&](int slab, int nk, int half) -> bf16x8 {
    int row = nk * 16 + l15;                       // row & 7 == l15 & 7
    int chunk = (half * 4 + g) ^ (l15 & 7);
    return *reinterpret_cast<const bf16x8*>(KV[slab] + row * 128 + chunk * 16);
  };
  auto vread = [&](int slab, int nkp, int ni) -> bf16x8 {
    int row = ni * 16 + l15;                       // row & 15 == l15
    int chunk = (nkp * 4 + g) ^ l15;
    return *reinterpret_cast<const bf16x8*>(KV[slab] + row * 256 + chunk * 16);
  };

  // ---- pass 1: row sum of exp(score); lane's q = l15, k = g*4+r within nk*16 ----
  float lr0 = 0.f, lr1 = 0.f, lr2 = 0.f, lr3 = 0.f;
  SK(0, 0);
  __syncthreads();
  for (int kt = 0; kt < 8; ++kt) {
    if (kt < 7) { SK((kt + 1) & 1, kt + 1); }
    else        { SK(0, 0); SV(2, 0); }  // pre-stage pass-2 entry
    const int ks = kt & 1;
#pragma unroll
    for (int nk = 0; nk < 8; ++nk) {
      f32x4 sc = {0.f, 0.f, 0.f, 0.f};
      sc = __builtin_amdgcn_mfma_f32_16x16x32_bf16(kread(ks, nk, 0), qf0, sc, 0, 0, 0);
      sc = __builtin_amdgcn_mfma_f32_16x16x32_bf16(kread(ks, nk, 1), qf1, sc, 0, 0, 0);
      lr0 += __expf(sc[0]); lr1 += __expf(sc[1]);
      lr2 += __expf(sc[2]); lr3 += __expf(sc[3]);
    }
    __syncthreads();
  }
  float lsum = (lr0 + lr1) + (lr2 + lr3);
  lsum += __shfl_xor(lsum, 16, 64);
  lsum += __shfl_xor(lsum, 32, 64);
  const float rl = 1.f / lsum;

  float* const prow = probs + ((size_t)bh * Ss + q0 + l15) * Ss;
  f32x4 cacc[4] = {};

  // ---- pass 2 (ascending; K[kt] in slab kt&1, V[kt] in slab 2+(kt&1)) ----
  for (int kt = 0; kt < 8; ++kt) {
    if (kt < 7) { SK((kt + 1) & 1, kt + 1); SV(2 + ((kt + 1) & 1), kt + 1); }
    const int ks = kt & 1, vs = 2 + (kt & 1);
#pragma unroll
    for (int nkp = 0; nkp < 4; ++nkp) {
#pragma unroll
      for (int h = 0; h < 2; ++h) {
        int nk = nkp * 2 + h;
        f32x4 sc = {0.f, 0.f, 0.f, 0.f};
        sc = __builtin_amdgcn_mfma_f32_16x16x32_bf16(kread(ks, nk, 0), qf0, sc, 0, 0, 0);
        sc = __builtin_amdgcn_mfma_f32_16x16x32_bf16(kread(ks, nk, 1), qf1, sc, 0, 0, 0);
        f32x4 pv;
#pragma unroll
        for (int r = 0; r < 4; ++r) pv[r] = __expf(sc[r]) * rl;
        *reinterpret_cast<f32x4*>(prow + kt * 128 + nk * 16 + g * 4) = pv;  // plain store
        bf16x4 pb = { (bf16)pv[0], (bf16)pv[1], (bf16)pv[2], (bf16)pv[3] };
        *reinterpret_cast<bf16x4*>(&Ps[w][l15][h * 16 + g * 4]) = pb;       // one ds_write_b64
      }
      // PV over this 32-wide k chunk; P and V from LDS (same-wave DS is in-order)
      bf16x8 pf = *reinterpret_cast<const bf16x8*>(&Ps[w][l15][g * 8]);
#pragma unroll
      for (int ni = 0; ni < 4; ++ni)
        cacc[ni] = __builtin_amdgcn_mfma_f32_16x16x32_bf16(pf, vread(vs, nkp, ni), cacc[ni], 0, 0, 0);
    }
    __syncthreads();
  }
#undef SK
#undef SV

  // ctx: [b][s][h*64+hd] bf16 (PV D layout: row g*4+r = q offset, col l15 = hd)
  const int bb = bh >> 4, hh = bh & 15;
#pragma unroll
  for (int ni = 0; ni < 4; ++ni)
#pragma unroll
    for (int r = 0; r < 4; ++r) {
      int q = q0 + g * 4 + r;
      ctx[((size_t)bb * Ss + q) * Dd + hh * 64 + ni * 16 + l15] = (bf16)cacc[ni][r];
    }
}

// ---------------- launch ----------------
extern "C" void kernel_launch(void* const* d_in, const int* in_sizes, int n_in,
                              void* d_out, int out_size, void* d_ws, size_t ws_size,
                              hipStream_t stream) {
  (void)in_sizes; (void)n_in; (void)out_size; (void)ws_size;
  const float* x   = (const float*)d_in[0];
  const float* Wq  = (const float*)d_in[1];
  const float* bq  = (const float*)d_in[2];
  const float* Wk  = (const float*)d_in[3];
  const float* bk  = (const float*)d_in[4];
  const float* Wv  = (const float*)d_in[5];
  const float* bv  = (const float*)d_in[6];
  const float* Wf  = (const float*)d_in[7];
  const float* bfp = (const float*)d_in[8];

  char* ws = (char*)d_ws;
  size_t off = 0;
  auto alloc = [&](size_t n) { void* p = ws + off; off += (n + 255) & ~(size_t)255; return p; };
  bf16* xb   = (bf16*)alloc((size_t)Mm * Dd * 2);
  bf16* wqb  = (bf16*)alloc((size_t)Dd * Dd * 2);
  bf16* wkb  = (bf16*)alloc((size_t)Dd * Dd * 2);
  bf16* wvb  = (bf16*)alloc((size_t)Dd * Dd * 2);
  bf16* wfb  = (bf16*)alloc((size_t)Dd * Dd * 2);
  bf16* Qb   = (bf16*)alloc((size_t)Mm * Dd * 2);
  bf16* Kb   = (bf16*)alloc((size_t)Mm * Dd * 2);
  bf16* Vtb  = (bf16*)alloc((size_t)Mm * Dd * 2);
  bf16* ctxb = (bf16*)alloc((size_t)Mm * Dd * 2);

  CastArgs ca;
  ca.src[0] = x;  ca.dst[0] = xb;  int n0 = Mm * Dd / 4;
  ca.src[1] = Wq; ca.dst[1] = wqb; int nw = Dd * Dd / 4;
  ca.src[2] = Wk; ca.dst[2] = wkb;
  ca.src[3] = Wv; ca.dst[3] = wvb;
  ca.src[4] = Wf; ca.dst[4] = wfb;
  ca.cum[0] = n0; ca.cum[1] = n0 + nw; ca.cum[2] = n0 + 2 * nw;
  ca.cum[3] = n0 + 3 * nw; ca.cum[4] = n0 + 4 * nw;
  int tot = ca.cum[4];
  cast_all<<<(tot + 255) / 256, 256, 0, stream>>>(ca, tot);

  gemm_qkv<<<dim3(Mm / 128, Dd / 128, 3), 256, 0, stream>>>(xb, wqb, wkb, wvb, bq, bk, bv, Qb, Kb, Vtb);

  float* probs = (float*)d_out + (size_t)Mm * Dd;
  attn_fused<<<dim3(Bb * Hh * 8), 512, 0, stream>>>(Qb, Kb, Vtb, probs, ctxb);

  gemm_out<<<dim3(Dd / 128, Mm / 128), 256, 0, stream>>>(ctxb, wfb, bfp, (float*)d_out);
}

// Round 6
// 263.848 us; speedup vs baseline: 1.3027x; 1.0008x over previous
//
#include <hip/hip_runtime.h>

typedef __bf16 bf16;
typedef __bf16 bf16x4 __attribute__((ext_vector_type(4)));
typedef __bf16 bf16x8 __attribute__((ext_vector_type(8)));
typedef float  f32x4  __attribute__((ext_vector_type(4)));

constexpr int Bb = 8, Ss = 1024, Dd = 1024, Hh = 16, HDd = 64;
constexpr int Mm = Bb * Ss;   // 8192
constexpr int Kk = 1024;

// ---------------- fused cast f32 -> bf16 (5 segments, float4 chunks) ----------------
struct CastArgs {
  const float* src[5];
  bf16* dst[5];
  int cum[5];
};
__global__ void cast_all(CastArgs a, int tot) {
  int i = blockIdx.x * blockDim.x + threadIdx.x;
  if (i >= tot) return;
  int s, base;
  if (i < a.cum[0])      { s = 0; base = 0; }
  else if (i < a.cum[1]) { s = 1; base = a.cum[0]; }
  else if (i < a.cum[2]) { s = 2; base = a.cum[1]; }
  else if (i < a.cum[3]) { s = 3; base = a.cum[2]; }
  else                   { s = 4; base = a.cum[3]; }
  int j = i - base;
  float4 v = reinterpret_cast<const float4*>(a.src[s])[j];
  bf16x4 o = { (bf16)v.x, (bf16)v.y, (bf16)v.z, (bf16)v.w };
  reinterpret_cast<bf16x4*>(a.dst[s])[j] = o;
}

// ---------------- shared NT GEMM core: 128x128 tile, BK=64, XOR-swizzled LDS ----------------
__device__ __forceinline__ void gemm_loop(const bf16* __restrict__ A, const bf16* __restrict__ Bm,
                                          int bm, int bn, unsigned char* As, unsigned char* Bs,
                                          int w, int lane, int l15, int g, f32x4 (&acc)[4][4]) {
  const bf16* srcA[4];
  const bf16* srcB[4];
#pragma unroll
  for (int i = 0; i < 4; ++i) {
    int gch = (w * 4 + i) * 64 + lane;  // chunk id 0..1023
    int r = gch >> 3, c = gch & 7, cs = c ^ (r & 7);
    srcA[i] = A  + (size_t)(bm * 128 + r) * Kk + cs * 8;
    srcB[i] = Bm + (size_t)(bn * 128 + r) * Kk + cs * 8;
  }
  for (int kt = 0; kt < Kk / 64; ++kt) {
    __syncthreads();
#pragma unroll
    for (int i = 0; i < 4; ++i) {
      __builtin_amdgcn_global_load_lds(
          (const __attribute__((address_space(1))) void*)(srcA[i] + kt * 64),
          (__attribute__((address_space(3))) void*)(As + (w * 4 + i) * 1024), 16, 0, 0);
      __builtin_amdgcn_global_load_lds(
          (const __attribute__((address_space(1))) void*)(srcB[i] + kt * 64),
          (__attribute__((address_space(3))) void*)(Bs + (w * 4 + i) * 1024), 16, 0, 0);
    }
    __syncthreads();
#pragma unroll
    for (int kk = 0; kk < 2; ++kk) {
      const int kb = kk * 64 + g * 16;
      bf16x8 af[4], bfr[4];
#pragma unroll
      for (int mi = 0; mi < 4; ++mi) {
        int row = ((w >> 1) * 64) + mi * 16 + l15;
        af[mi] = *reinterpret_cast<const bf16x8*>(As + row * 128 + (kb ^ ((row & 7) << 4)));
      }
#pragma unroll
      for (int ni = 0; ni < 4; ++ni) {
        int row = ((w & 1) * 64) + ni * 16 + l15;
        bfr[ni] = *reinterpret_cast<const bf16x8*>(Bs + row * 128 + (kb ^ ((row & 7) << 4)));
      }
#pragma unroll
      for (int mi = 0; mi < 4; ++mi)
#pragma unroll
        for (int ni = 0; ni < 4; ++ni)
          acc[mi][ni] = __builtin_amdgcn_mfma_f32_16x16x32_bf16(af[mi], bfr[ni], acc[mi][ni], 0, 0, 0);
    }
  }
}

// ---------------- fused QKV projection ----------------
// z=0: Q = (x@Wq^T + bq)*0.125 -> [b,h,s,hd]; z=1: K -> [b,h,s,hd]; z=2: V^T -> [b,h,hd,s]
__global__ __launch_bounds__(256) void gemm_qkv(const bf16* __restrict__ x,
                                                const bf16* __restrict__ wq, const bf16* __restrict__ wk,
                                                const bf16* __restrict__ wv,
                                                const float* __restrict__ bq, const float* __restrict__ bk,
                                                const float* __restrict__ bv,
                                                bf16* __restrict__ Qo, bf16* __restrict__ Ko,
                                                bf16* __restrict__ Vto) {
  const int tid = threadIdx.x;
  const int lane = tid & 63;
  const int w = tid >> 6;
  const int l15 = lane & 15, g = lane >> 4;
  const int z = blockIdx.z;

  const bf16* A; const bf16* Bm; int bm, bn;
  if (z < 2) { A = x; Bm = z ? wk : wq; bm = blockIdx.x; bn = blockIdx.y; }
  else       { A = wv; Bm = x;          bm = blockIdx.y; bn = blockIdx.x; }

  __shared__ __align__(16) unsigned char As[128 * 128];
  __shared__ __align__(16) unsigned char Bs[128 * 128];
  f32x4 acc[4][4] = {};
  gemm_loop(A, Bm, bm, bn, As, Bs, w, lane, l15, g, acc);

  const int wr = (w >> 1) * 64, wc = (w & 1) * 64;
  if (z < 2) {
    const float* bias = z ? bk : bq;
    bf16* out = z ? Ko : Qo;
    const float scale = z ? 1.f : 0.125f;
#pragma unroll
    for (int ni = 0; ni < 4; ++ni) {
      int col = bn * 128 + wc + ni * 16 + l15;
      float bv_ = bias[col];
#pragma unroll
      for (int mi = 0; mi < 4; ++mi)
#pragma unroll
        for (int r = 0; r < 4; ++r) {
          int row = bm * 128 + wr + mi * 16 + g * 4 + r;
          float val = (acc[mi][ni][r] + bv_) * scale;
          size_t adr = ((size_t)((row >> 10) * Hh + (col >> 6)) * Ss + (row & 1023)) * HDd + (col & 63);
          out[adr] = (bf16)val;
        }
    }
  } else {  // V^T: row = d-index, col = bs-index, bias per row
#pragma unroll
    for (int mi = 0; mi < 4; ++mi)
#pragma unroll
      for (int r = 0; r < 4; ++r) {
        int row = bm * 128 + wr + mi * 16 + g * 4 + r;
        float bv_ = bv[row];
#pragma unroll
        for (int ni = 0; ni < 4; ++ni) {
          int col = bn * 128 + wc + ni * 16 + l15;
          size_t adr = ((size_t)((col >> 10) * Hh + (row >> 6)) * HDd + (row & 63)) * Ss + (col & 1023);
          Vto[adr] = (bf16)(acc[mi][ni][r] + bv_);
        }
      }
  }
}

// ---------------- final projection: out = ctx @ Wf^T + bf (f32) ----------------
__global__ __launch_bounds__(256) void gemm_out(const bf16* __restrict__ A, const bf16* __restrict__ Bm,
                                                const float* __restrict__ bias, float* __restrict__ out) {
  const int tid = threadIdx.x;
  const int lane = tid & 63;
  const int w = tid >> 6;
  const int l15 = lane & 15, g = lane >> 4;
  const int bn = blockIdx.x, bm = blockIdx.y;
  __shared__ __align__(16) unsigned char As[128 * 128];
  __shared__ __align__(16) unsigned char Bs[128 * 128];
  f32x4 acc[4][4] = {};
  gemm_loop(A, Bm, bm, bn, As, Bs, w, lane, l15, g, acc);
  const int wr = (w >> 1) * 64, wc = (w & 1) * 64;
#pragma unroll
  for (int ni = 0; ni < 4; ++ni) {
    int col = bn * 128 + wc + ni * 16 + l15;
    float bv_ = bias[col];
#pragma unroll
    for (int mi = 0; mi < 4; ++mi)
#pragma unroll
      for (int r = 0; r < 4; ++r) {
        int row = bm * 128 + wr + mi * 16 + g * 4 + r;
        out[(size_t)row * Dd + col] = acc[mi][ni][r] + bv_;
      }
  }
}

// ---------------- fused attention ----------------
// 1024 blocks, 512 threads = 8 waves, wave owns 16 q rows. KVBLK=128, 8 kt phases per pass.
// T4 counted-vmcnt schedule (raw s_barrier, never vmcnt(0) mid-loop):
//   pass 1: K rotates through ALL 4 slabs (prefetch depth 3 covers ~900cyc HBM latency);
//           per-phase waits vmcnt(4/2/0) by exact per-wave queue count.
//   pass 2: K dbuf slabs 0/1, V dbuf slabs 2/3; per-phase wait vmcnt(8) = the 8 current-phase
//           probs stores -> retires the 4 next-tile loads (older in queue), stores stay in
//           flight across the barrier.  sched_barrier(0) pins load-issue before compute
//           (keeps queue counts exact) and fences ds_reads after each barrier (rule #18).
// Swapped QK^T (mfma(K,Q)): lane l15 = q row, g*4+r = k positions -> f32x4 probs stores,
// 2-shuffle l-reduce. T5 setprio around MFMA clusters.
#define WAITV(n) asm volatile("s_waitcnt vmcnt(" #n ")" ::: "memory")
#define PHASE_BAR { __builtin_amdgcn_s_barrier(); __builtin_amdgcn_sched_barrier(0); }

__global__ __launch_bounds__(512, 4) void attn_fused(const bf16* __restrict__ Q,
                                                     const bf16* __restrict__ Kt,
                                                     const bf16* __restrict__ Vt,
                                                     float* __restrict__ probs,
                                                     bf16* __restrict__ ctx) {
  const int tid = threadIdx.x;
  const int lane = tid & 63;
  const int w = tid >> 6;
  const int l15 = lane & 15, g = lane >> 4;
  const int bid = blockIdx.x;
  const int bh = (bid & 7) * 16 + ((bid >> 3) & 15);  // same head -> same bid%8 -> same XCD
  const int qt = bid >> 7;
  const int q0 = qt * 128 + w * 16;

  __shared__ __align__(16) unsigned char KV[4][16384];  // p1: K rotation; p2: K slabs 0/1, V 2/3
  __shared__ __align__(16) bf16 Ps[8][16][40];          // per-wave P chunk (32 k + pad)

  // Q fragment (B-operand): lane holds Q[q0+l15][g*8..+7] and +32 (pre-scaled by 1/8)
  bf16x8 qf0, qf1;
  {
    const bf16* qp = Q + ((size_t)bh * Ss + q0 + l15) * HDd + g * 8;
    qf0 = *reinterpret_cast<const bf16x8*>(qp);
    qf1 = *reinterpret_cast<const bf16x8*>(qp + 32);
  }
  const bf16* kbase = Kt + (size_t)bh * Ss * HDd;
  const bf16* vbase = Vt + (size_t)bh * HDd * Ss;

  // staging sources (source chunk pre-swizzled; global_load_lds dest = wave base + lane*16)
  const bf16* ksrc[2];
  const bf16* vsrc[2];
#pragma unroll
  for (int i = 0; i < 2; ++i) {
    int ch = i * 512 + tid;
    int kr = ch >> 3, kc = (ch & 7) ^ (kr & 7);
    ksrc[i] = kbase + (size_t)kr * HDd + kc * 8;
    int vr = ch >> 4, vc = (ch & 15) ^ (vr & 15);
    vsrc[i] = vbase + (size_t)vr * Ss + vc * 8;
  }

#define SK(slab, t)                                                                       \
  {                                                                                       \
    _Pragma("unroll") for (int i = 0; i < 2; ++i)                                         \
        __builtin_amdgcn_global_load_lds(                                                 \
            (const __attribute__((address_space(1))) void*)(ksrc[i] + (size_t)(t) * 128 * HDd), \
            (__attribute__((address_space(3))) void*)(KV[slab] + (i * 512 + w * 64) * 16),\
            16, 0, 0);                                                                    \
  }
#define SV(slab, t)                                                                       \
  {                                                                                       \
    _Pragma("unroll") for (int i = 0; i < 2; ++i)                                         \
        __builtin_amdgcn_global_load_lds(                                                 \
            (const __attribute__((address_space(1))) void*)(vsrc[i] + (t) * 128),         \
            (__attribute__((address_space(3))) void*)(KV[slab] + (i * 512 + w * 64) * 16),\
            16, 0, 0);                                                                    \
  }

  auto kread = [&](int slab, int nk, int half) -> bf16x8 {
    int row = nk * 16 + l15;                       // row & 7 == l15 & 7
    int chunk = (half * 4 + g) ^ (l15 & 7);
    return *reinterpret_cast<const bf16x8*>(KV[slab] + row * 128 + chunk * 16);
  };
  auto vread = [&](int slab, int nkp, int ni) -> bf16x8 {
    int row = ni * 16 + l15;                       // row & 15 == l15
    int chunk = (nkp * 4 + g) ^ l15;
    return *reinterpret_cast<const bf16x8*>(KV[slab] + row * 256 + chunk * 16);
  };

  // ---- pass 1: row sum of exp(score); lane's q = l15, k = g*4+r within nk*16 ----
  float lr0 = 0.f, lr1 = 0.f, lr2 = 0.f, lr3 = 0.f;
  SK(0, 0); SK(1, 1); SK(2, 2);     // prefetch depth 3
  __builtin_amdgcn_sched_barrier(0);
  WAITV(4);                          // K0 retired (K1,K2 in flight)
  PHASE_BAR;
  for (int kt = 0; kt < 8; ++kt) {
    if (kt <= 4)      { SK((kt + 3) & 3, kt + 3); }
    else if (kt == 7) { SK(0, 0); SV(2, 0); }     // pre-stage pass-2 entry
    __builtin_amdgcn_sched_barrier(0);
    const int ks = kt & 3;
#pragma unroll
    for (int nk = 0; nk < 8; ++nk) {
      f32x4 sc = {0.f, 0.f, 0.f, 0.f};
      bf16x8 k0 = kread(ks, nk, 0), k1 = kread(ks, nk, 1);
      __builtin_amdgcn_s_setprio(1);
      sc = __builtin_amdgcn_mfma_f32_16x16x32_bf16(k0, qf0, sc, 0, 0, 0);
      sc = __builtin_amdgcn_mfma_f32_16x16x32_bf16(k1, qf1, sc, 0, 0, 0);
      __builtin_amdgcn_s_setprio(0);
      lr0 += __expf(sc[0]); lr1 += __expf(sc[1]);
      lr2 += __expf(sc[2]); lr3 += __expf(sc[3]);
    }
    // per-wave queue: tiles outstanding after this phase's needs
    if (kt <= 4)      { WAITV(4); }  // next tile retired; 2 tiles (4 loads) in flight
    else if (kt == 5) { WAITV(2); }
    else              { WAITV(0); }  // kt=6: K7; kt=7: K0+V0 for pass 2
    PHASE_BAR;
  }
  float lsum = (lr0 + lr1) + (lr2 + lr3);
  lsum += __shfl_xor(lsum, 16, 64);
  lsum += __shfl_xor(lsum, 32, 64);
  const float rl = 1.f / lsum;

  float* const prow = probs + ((size_t)bh * Ss + q0 + l15) * Ss;
  f32x4 cacc[4] = {};

  // ---- pass 2 (ascending; K[kt] slab kt&1, V[kt] slab 2+(kt&1); K0/V0 staged above) ----
  for (int kt = 0; kt < 8; ++kt) {
    if (kt < 7) { SK((kt + 1) & 1, kt + 1); SV(2 + ((kt + 1) & 1), kt + 1); }
    __builtin_amdgcn_sched_barrier(0);   // pin the 4 loads before compute (exact queue count)
    const int ks = kt & 1, vs = 2 + (kt & 1);
#pragma unroll
    for (int nkp = 0; nkp < 4; ++nkp) {
#pragma unroll
      for (int h = 0; h < 2; ++h) {
        int nk = nkp * 2 + h;
        f32x4 sc = {0.f, 0.f, 0.f, 0.f};
        bf16x8 k0 = kread(ks, nk, 0), k1 = kread(ks, nk, 1);
        __builtin_amdgcn_s_setprio(1);
        sc = __builtin_amdgcn_mfma_f32_16x16x32_bf16(k0, qf0, sc, 0, 0, 0);
        sc = __builtin_amdgcn_mfma_f32_16x16x32_bf16(k1, qf1, sc, 0, 0, 0);
        __builtin_amdgcn_s_setprio(0);
        f32x4 pv;
#pragma unroll
        for (int r = 0; r < 4; ++r) pv[r] = __expf(sc[r]) * rl;
        *reinterpret_cast<f32x4*>(prow + kt * 128 + nk * 16 + g * 4) = pv;
        bf16x4 pb = { (bf16)pv[0], (bf16)pv[1], (bf16)pv[2], (bf16)pv[3] };
        *reinterpret_cast<bf16x4*>(&Ps[w][l15][h * 16 + g * 4]) = pb;  // one ds_write_b64
      }
      bf16x8 pf = *reinterpret_cast<const bf16x8*>(&Ps[w][l15][g * 8]);
      bf16x8 vf0 = vread(vs, nkp, 0), vf1 = vread(vs, nkp, 1);
      bf16x8 vf2 = vread(vs, nkp, 2), vf3 = vread(vs, nkp, 3);
      __builtin_amdgcn_s_setprio(1);
      cacc[0] = __builtin_amdgcn_mfma_f32_16x16x32_bf16(pf, vf0, cacc[0], 0, 0, 0);
      cacc[1] = __builtin_amdgcn_mfma_f32_16x16x32_bf16(pf, vf1, cacc[1], 0, 0, 0);
      cacc[2] = __builtin_amdgcn_mfma_f32_16x16x32_bf16(pf, vf2, cacc[2], 0, 0, 0);
      cacc[3] = __builtin_amdgcn_mfma_f32_16x16x32_bf16(pf, vf3, cacc[3], 0, 0, 0);
      __builtin_amdgcn_s_setprio(0);
    }
    if (kt < 7) {
      WAITV(8);   // retires the 4 next-tile loads; the 8 current probs stores stay in flight
      PHASE_BAR;
    }
  }
#undef SK
#undef SV

  // ctx: [b][s][h*64+hd] bf16 (PV D layout: row g*4+r = q offset, col l15 = hd)
  const int bb = bh >> 4, hh = bh & 15;
#pragma unroll
  for (int ni = 0; ni < 4; ++ni)
#pragma unroll
    for (int r = 0; r < 4; ++r) {
      int q = q0 + g * 4 + r;
      ctx[((size_t)bb * Ss + q) * Dd + hh * 64 + ni * 16 + l15] = (bf16)cacc[ni][r];
    }
}

// ---------------- launch ----------------
extern "C" void kernel_launch(void* const* d_in, const int* in_sizes, int n_in,
                              void* d_out, int out_size, void* d_ws, size_t ws_size,
                              hipStream_t stream) {
  (void)in_sizes; (void)n_in; (void)out_size; (void)ws_size;
  const float* x   = (const float*)d_in[0];
  const float* Wq  = (const float*)d_in[1];
  const float* bq  = (const float*)d_in[2];
  const float* Wk  = (const float*)d_in[3];
  const float* bk  = (const float*)d_in[4];
  const float* Wv  = (const float*)d_in[5];
  const float* bv  = (const float*)d_in[6];
  const float* Wf  = (const float*)d_in[7];
  const float* bfp = (const float*)d_in[8];

  char* ws = (char*)d_ws;
  size_t off = 0;
  auto alloc = [&](size_t n) { void* p = ws + off; off += (n + 255) & ~(size_t)255; return p; };
  bf16* xb   = (bf16*)alloc((size_t)Mm * Dd * 2);
  bf16* wqb  = (bf16*)alloc((size_t)Dd * Dd * 2);
  bf16* wkb  = (bf16*)alloc((size_t)Dd * Dd * 2);
  bf16* wvb  = (bf16*)alloc((size_t)Dd * Dd * 2);
  bf16* wfb  = (bf16*)alloc((size_t)Dd * Dd * 2);
  bf16* Qb   = (bf16*)alloc((size_t)Mm * Dd * 2);
  bf16* Kb   = (bf16*)alloc((size_t)Mm * Dd * 2);
  bf16* Vtb  = (bf16*)alloc((size_t)Mm * Dd * 2);
  bf16* ctxb = (bf16*)alloc((size_t)Mm * Dd * 2);

  CastArgs ca;
  ca.src[0] = x;  ca.dst[0] = xb;  int n0 = Mm * Dd / 4;
  ca.src[1] = Wq; ca.dst[1] = wqb; int nw = Dd * Dd / 4;
  ca.src[2] = Wk; ca.dst[2] = wkb;
  ca.src[3] = Wv; ca.dst[3] = wvb;
  ca.src[4] = Wf; ca.dst[4] = wfb;
  ca.cum[0] = n0; ca.cum[1] = n0 + nw; ca.cum[2] = n0 + 2 * nw;
  ca.cum[3] = n0 + 3 * nw; ca.cum[4] = n0 + 4 * nw;
  int tot = ca.cum[4];
  cast_all<<<(tot + 255) / 256, 256, 0, stream>>>(ca, tot);

  gemm_qkv<<<dim3(Mm / 128, Dd / 128, 3), 256, 0, stream>>>(xb, wqb, wkb, wvb, bq, bk, bv, Qb, Kb, Vtb);

  float* probs = (float*)d_out + (size_t)Mm * Dd;
  attn_fused<<<dim3(Bb * Hh * 8), 512, 0, stream>>>(Qb, Kb, Vtb, probs, ctxb);

  gemm_out<<<dim3(Dd / 128, Mm / 128), 256, 0, stream>>>(ctxb, wfb, bfp, (float*)d_out);
}